// Round 9
// baseline (2091.264 us; speedup 1.0000x reference)
//
#include <hip/hip_runtime.h>
#include <hip/hip_bf16.h>
#include <math.h>

// PPOActorRNN on MI355X — round 13: 128-row dual-half jobs (2x W reuse).
// R8 falsified stale-spin theory (RMW-poll slightly worse). Re-audit: W-load
// traffic = 768 KB/job x ~560 jobs/shard ~ 330 MB per XCD L2/LLC per GRU —
// that is the ~50us/round, not the barrier. Fix: 128-row tiles — each W
// fragment feeds 96 MFMAs (8 row-groups) instead of 48; W traffic halves;
// compute per W-load (~480cy with 3-deep prefetch) covers LLC latency.
// Sync = R7 verbatim (best passing: 879us GRU). acc 256 VGPR -> occ 1
// block/CU (proven non-binding). LDS 64KB staging.

#define TTT 256
#define BBB 256
#define DDD 512
#define ACT 32
#define MMM (TTT*BBB)

typedef short bf16x8 __attribute__((ext_vector_type(8)));
typedef float f32x4 __attribute__((ext_vector_type(4)));
typedef unsigned short u16;

__device__ inline u16 f2bf(float f) {
    unsigned int u = __float_as_uint(f);
    u += 0x7fffu + ((u >> 16) & 1u);
    return (u16)(u >> 16);
}
__device__ inline float bf2f(u16 h) { return __uint_as_float(((unsigned int)h) << 16); }

#define AL_RLX(p)  __hip_atomic_load((p), __ATOMIC_RELAXED, __HIP_MEMORY_SCOPE_AGENT)

// ---------------- transpose + cvt: out[n*ostride + k] = bf16(in[k*512 + n]) ----
__global__ __launch_bounds__(256) void transpose_cvt_k(
    const float* __restrict__ in, u16* __restrict__ out, int ostride)
{
    __shared__ float tile[32][33];
    const int c = threadIdx.x & 31;
    const int r0 = threadIdx.x >> 5;
    const int bx = blockIdx.x, by = blockIdx.y;
#pragma unroll
    for (int p = 0; p < 4; p++) {
        int r = r0 + p * 8;
        tile[r][c] = in[(size_t)(by * 32 + r) * DDD + bx * 32 + c];
    }
    __syncthreads();
#pragma unroll
    for (int p = 0; p < 4; p++) {
        int r = r0 + p * 8;
        out[(size_t)(bx * 32 + r) * ostride + by * 32 + c] = f2bf(tile[c][r]);
    }
}

// ---------------- MFMA GEMM (parallel phases), unchanged ----------------
template<bool AF32>
__global__ __launch_bounds__(256) void gemm_bf16_k(
    const void* __restrict__ Aptr, const u16* __restrict__ Bt,
    const float* __restrict__ bias, u16* __restrict__ C, int N)
{
    __shared__ u16 As[128 * 64];
    __shared__ u16 Bs[128 * 64];
    const int tid = threadIdx.x;
    const int row0 = blockIdx.x * 128;
    const int col0 = blockIdx.y * 128;
    const int lane = tid & 63, wid = tid >> 6;
    const int wr = wid >> 1, wc = wid & 1;
    const int lm = lane & 15, lq = lane >> 4;

    f32x4 acc[4][4];
#pragma unroll
    for (int i = 0; i < 4; i++)
#pragma unroll
        for (int j = 0; j < 4; j++) acc[i][j] = (f32x4){0.f, 0.f, 0.f, 0.f};

    for (int kc = 0; kc < 8; kc++) {
        const int k0 = kc * 64;
#pragma unroll
        for (int p = 0; p < 4; p++) {
            int g = p * 256 + tid;
            int row = g >> 3, j = g & 7;
            bf16x8 v;
            if (AF32) {
                const float* s = (const float*)Aptr + (size_t)(row0 + row) * DDD + k0 + j * 8;
                float4 a0 = *(const float4*)s;
                float4 a1 = *(const float4*)(s + 4);
                v[0] = (short)f2bf(a0.x); v[1] = (short)f2bf(a0.y);
                v[2] = (short)f2bf(a0.z); v[3] = (short)f2bf(a0.w);
                v[4] = (short)f2bf(a1.x); v[5] = (short)f2bf(a1.y);
                v[6] = (short)f2bf(a1.z); v[7] = (short)f2bf(a1.w);
            } else {
                v = *(const bf16x8*)((const u16*)Aptr + (size_t)(row0 + row) * DDD + k0 + j * 8);
            }
            *(bf16x8*)(As + row * 64 + ((j ^ (row & 7)) << 3)) = v;
        }
#pragma unroll
        for (int p = 0; p < 4; p++) {
            int g = p * 256 + tid;
            int n = g >> 3, j = g & 7;
            bf16x8 v = *(const bf16x8*)(Bt + (size_t)(col0 + n) * DDD + k0 + j * 8);
            *(bf16x8*)(Bs + n * 64 + ((j ^ (n & 7)) << 3)) = v;
        }
        __syncthreads();
#pragma unroll
        for (int ks = 0; ks < 2; ks++) {
            bf16x8 af[4], bfr[4];
#pragma unroll
            for (int i = 0; i < 4; i++) {
                int row = wr * 64 + i * 16 + lm;
                af[i] = *(const bf16x8*)(As + row * 64 + (((ks * 4 + lq) ^ (row & 7)) << 3));
            }
#pragma unroll
            for (int j = 0; j < 4; j++) {
                int n = wc * 64 + j * 16 + lm;
                bfr[j] = *(const bf16x8*)(Bs + n * 64 + (((ks * 4 + lq) ^ (n & 7)) << 3));
            }
#pragma unroll
            for (int i = 0; i < 4; i++)
#pragma unroll
                for (int j = 0; j < 4; j++)
                    acc[i][j] = __builtin_amdgcn_mfma_f32_16x16x32_bf16(af[i], bfr[j], acc[i][j], 0, 0, 0);
        }
        __syncthreads();
    }
#pragma unroll
    for (int j = 0; j < 4; j++) {
        int col = col0 + wc * 64 + j * 16 + lm;
        float bj = bias[col];
#pragma unroll
        for (int i = 0; i < 4; i++) {
            int rb = row0 + wr * 64 + i * 16 + lq * 4;
#pragma unroll
            for (int r = 0; r < 4; r++)
                C[(size_t)(rb + r) * N + col] = f2bf(acc[i][j][r] + bj);
        }
    }
}

// ---------------- LayerNorm + ReLU in-place on bf16 [M x 512] ----------------
__global__ __launch_bounds__(256) void ln_relu_k(
    u16* __restrict__ X, const float* __restrict__ gamma, const float* __restrict__ beta)
{
    const int tid = threadIdx.x;
    const int lane = tid & 63;
    const size_t row = (size_t)blockIdx.x * 4 + (tid >> 6);
    const int c0 = lane * 8;
    u16* px = X + row * DDD + c0;
    bf16x8 v = *(const bf16x8*)px;
    float f[8]; float s = 0.f, s2 = 0.f;
#pragma unroll
    for (int i = 0; i < 8; i++) { f[i] = bf2f((u16)v[i]); s += f[i]; s2 += f[i] * f[i]; }
#pragma unroll
    for (int off = 32; off; off >>= 1) { s += __shfl_xor(s, off); s2 += __shfl_xor(s2, off); }
    float mu = s * (1.f / (float)DDD);
    float rs = rsqrtf(s2 * (1.f / (float)DDD) - mu * mu + 1e-6f);
    float4 g0 = *(const float4*)(gamma + c0), g1 = *(const float4*)(gamma + c0 + 4);
    float4 b0 = *(const float4*)(beta + c0),  b1 = *(const float4*)(beta + c0 + 4);
    float gg[8] = {g0.x, g0.y, g0.z, g0.w, g1.x, g1.y, g1.z, g1.w};
    float bb[8] = {b0.x, b0.y, b0.z, b0.w, b1.x, b1.y, b1.z, b1.w};
    bf16x8 o;
#pragma unroll
    for (int i = 0; i < 8; i++) {
        float yv = (f[i] - mu) * rs * gg[i] + bb[i];
        o[i] = (short)f2bf(fmaxf(yv, 0.f));
    }
    *(bf16x8*)px = o;
}

// ---------------- logits ----------------
__global__ __launch_bounds__(256) void logits_k(
    const u16* __restrict__ AM, const float* __restrict__ Wa,
    const float* __restrict__ ba, const int* __restrict__ avail,
    float* __restrict__ out)
{
    __shared__ float xs[8][DDD];
    const int tid = threadIdx.x;
    const size_t row0 = (size_t)blockIdx.x * 8;
    for (int g = tid; g < 8 * 64; g += 256) {
        int r = g >> 6, c8 = (g & 63) * 8;
        bf16x8 v = *(const bf16x8*)(AM + (row0 + r) * DDD + c8);
#pragma unroll
        for (int i = 0; i < 8; i++) xs[r][c8 + i] = bf2f((u16)v[i]);
    }
    __syncthreads();
    const int r = tid >> 5, a = tid & 31;
    float acc = 0.f;
    for (int k = 0; k < DDD; k += 4) {
        float4 xv = *(const float4*)&xs[r][k];
        acc = fmaf(xv.x, Wa[(k + 0) * ACT + a], acc);
        acc = fmaf(xv.y, Wa[(k + 1) * ACT + a], acc);
        acc = fmaf(xv.z, Wa[(k + 2) * ACT + a], acc);
        acc = fmaf(xv.w, Wa[(k + 3) * ACT + a], acc);
    }
    size_t o = (row0 + r) * ACT + a;
    float v = acc + ba[a];
    if (avail[o] == 0) v -= 1e10f;
    out[o] = v;
}

// ---------------- list building (per-XCD buckets) — R7 verbatim ----------------
__global__ __launch_bounds__(256) void depth_build_k(
    const int* __restrict__ dones,
    int* __restrict__ keyA, int* __restrict__ pidxA,
    int* __restrict__ counts, int* __restrict__ maxk)
{
    __shared__ int lc[8 * 512];
    __shared__ int lmax[8];
    const int b = threadIdx.x;
    const int e = b >> 5;
    for (int i = b; i < 8 * 512; i += 256) lc[i] = 0;
    if (b < 8) lmax[b] = 0;
    __syncthreads();
    int dprev = 0, mx = 0;
    for (int t = 0; t < TTT; t++) {
        int pos = t * BBB + b;
        int d, pi, k;
        if (dones[pos] != 0)       { d = 0; pi = -1;       k = 0; }
        else if (t == 0)           { d = 0; pi = -2 - b;   k = 1; }
        else                       { d = dprev + 1; pi = pos - BBB; k = d + 1; }
        keyA[pos] = k; pidxA[pos] = pi;
        atomicAdd(&lc[e * 512 + k], 1);
        mx = max(mx, k);
        dprev = d;
    }
    atomicMax(&lmax[e], mx);
    __syncthreads();
    for (int i = b; i < 8 * 512; i += 256) counts[i] = lc[i];
    if (b < 8) maxk[b] = lmax[b];
}

__global__ void scan_k(const int* __restrict__ counts, int* __restrict__ offs)
{
    int e = threadIdx.x;
    if (e < 8) {
        int s = 0;
        for (int i = 0; i < 512; i++) { offs[e * 512 + i] = s; s += counts[e * 512 + i]; }
    }
}

__global__ __launch_bounds__(256) void scatter_k(
    const int* __restrict__ keyA, const int* __restrict__ offs,
    int* __restrict__ cursor, int* __restrict__ list)
{
    __shared__ int lcnt[8 * 512];
    __shared__ int lbase[8 * 512];
    const int tid = threadIdx.x;
    for (int i = tid; i < 8 * 512; i += 256) lcnt[i] = 0;
    __syncthreads();
    int pos = blockIdx.x * 256 + tid;
    int b = pos & 255;
    int e = b >> 5;
    int k = keyA[pos];
    int rank = atomicAdd(&lcnt[e * 512 + k], 1);
    __syncthreads();
    for (int q = tid; q < 8 * 512; q += 256) {
        int c = lcnt[q];
        lbase[q] = c ? atomicAdd(&cursor[q], c) : 0;
    }
    __syncthreads();
    list[e * 8192 + offs[e * 512 + k] + lbase[e * 512 + k] + rank] = pos;
}

// ---------------- GRU job body: 128-row dual-half tile ----------------
template<bool YF32>
__device__ __forceinline__ void gru_job(
    const u16* __restrict__ E, const float* __restrict__ hidden,
    const u16* __restrict__ Wstk, const float* __restrict__ bi,
    const float* __restrict__ bhn,
    const int* __restrict__ list, const int* __restrict__ pidxA,
    void* __restrict__ Yv,
    int off, int nd, int rt, int panel,
    u16* As, int* posL, int* pidxL, int* sAnyH)
{
    const int tid = threadIdx.x;
    const int w = tid >> 6, lane = tid & 63;
    const int lm = lane & 15, lq = lane >> 4;

    if (tid == 0) *sAnyH = 0;
    __syncthreads();
    if (tid < 128) {
        int idx = rt * 128 + tid;
        int p = (idx < nd) ? list[off + idx] : -1;
        int pi = (p >= 0) ? pidxA[p] : -1;
        posL[tid] = p;
        pidxL[tid] = pi;
        bool hasH = (p >= 0) && (pi != -1);
        unsigned long long m = __ballot(hasH);
        if ((tid & 63) == 0 && m != 0ULL) atomicOr(sAnyH, 1);
    }
    __syncthreads();
    const bool skipH = !(*sAnyH);

    // acc for 128 rows x 32 gate-cols per wave: 8 row-groups of 16
    f32x4 a01[8][4], aX[8][2], aH[8][2];
#pragma unroll
    for (int mt = 0; mt < 8; mt++) {
#pragma unroll
        for (int q = 0; q < 4; q++) a01[mt][q] = (f32x4){0.f, 0.f, 0.f, 0.f};
#pragma unroll
        for (int q = 0; q < 2; q++) {
            aX[mt][q] = (f32x4){0.f, 0.f, 0.f, 0.f};
            aH[mt][q] = (f32x4){0.f, 0.f, 0.f, 0.f};
        }
    }

    const int cb = panel * 128 + w * 32;
    const u16* wp[6];
#pragma unroll
    for (int ct = 0; ct < 6; ct++) {
        int gate = ct >> 1;
        int nglob = gate * 512 + cb + ((ct & 1) << 4) + lm;
        wp[ct] = Wstk + (size_t)nglob * 1024 + lq * 8;
    }

    const int nkc = skipH ? 2 : 4;
    for (int kc = 0; kc < nkc; kc++) {
        // stage A chunk: 128 rows x 256 K (gathered rows)
#pragma unroll
        for (int it = 0; it < 16; it++) {
            int g = it * 256 + tid;
            int row = g >> 5, jg = g & 31;
            int kglob = kc * 256 + jg * 8;
            bf16x8 v = (bf16x8){0, 0, 0, 0, 0, 0, 0, 0};
            int p = posL[row];
            if (p >= 0) {
                if (kglob < 512) {
                    v = *(const bf16x8*)(E + (size_t)p * DDD + kglob);
                } else {
                    int k2 = kglob - 512;
                    int pi = pidxL[row];
                    if (pi >= 0) {
                        if (YF32) {
                            const float* s = (const float*)Yv + (size_t)pi * DDD + k2;
                            float4 a0 = *(const float4*)s;
                            float4 a1 = *(const float4*)(s + 4);
                            v[0] = (short)f2bf(a0.x); v[1] = (short)f2bf(a0.y);
                            v[2] = (short)f2bf(a0.z); v[3] = (short)f2bf(a0.w);
                            v[4] = (short)f2bf(a1.x); v[5] = (short)f2bf(a1.y);
                            v[6] = (short)f2bf(a1.z); v[7] = (short)f2bf(a1.w);
                        } else {
                            v = *(const bf16x8*)((const u16*)Yv + (size_t)pi * DDD + k2);
                        }
                    } else if (pi <= -2) {
                        const float* s = hidden + (size_t)(-pi - 2) * DDD + k2;
                        float4 a0 = *(const float4*)s;
                        float4 a1 = *(const float4*)(s + 4);
                        v[0] = (short)f2bf(a0.x); v[1] = (short)f2bf(a0.y);
                        v[2] = (short)f2bf(a0.z); v[3] = (short)f2bf(a0.w);
                        v[4] = (short)f2bf(a1.x); v[5] = (short)f2bf(a1.y);
                        v[6] = (short)f2bf(a1.z); v[7] = (short)f2bf(a1.w);
                    }
                }
            }
            *(bf16x8*)(As + row * 256 + ((jg ^ (row & 31)) << 3)) = v;
        }
        __syncthreads();

        const bool xpart = (kc < 2);
        const int kgb = kc * 256;
        bf16x8 bfA[6], bfB[6], bfC[6];

#define LOADW(B, KG) \
    _Pragma("unroll") \
    for (int ct = 0; ct < 6; ct++) B[ct] = *(const bf16x8*)(wp[ct] + (KG));

#define COMPW(B, S) \
    _Pragma("unroll") \
    for (int mt = 0; mt < 8; mt++) { \
        int row = mt * 16 + lm; \
        int jgr = (S) * 4 + lq; \
        bf16x8 af = *(const bf16x8*)(As + row * 256 + ((jgr ^ (row & 31)) << 3)); \
        a01[mt][0] = __builtin_amdgcn_mfma_f32_16x16x32_bf16(af, B[0], a01[mt][0], 0, 0, 0); \
        a01[mt][1] = __builtin_amdgcn_mfma_f32_16x16x32_bf16(af, B[1], a01[mt][1], 0, 0, 0); \
        a01[mt][2] = __builtin_amdgcn_mfma_f32_16x16x32_bf16(af, B[2], a01[mt][2], 0, 0, 0); \
        a01[mt][3] = __builtin_amdgcn_mfma_f32_16x16x32_bf16(af, B[3], a01[mt][3], 0, 0, 0); \
        if (xpart) { \
            aX[mt][0] = __builtin_amdgcn_mfma_f32_16x16x32_bf16(af, B[4], aX[mt][0], 0, 0, 0); \
            aX[mt][1] = __builtin_amdgcn_mfma_f32_16x16x32_bf16(af, B[5], aX[mt][1], 0, 0, 0); \
        } else { \
            aH[mt][0] = __builtin_amdgcn_mfma_f32_16x16x32_bf16(af, B[4], aH[mt][0], 0, 0, 0); \
            aH[mt][1] = __builtin_amdgcn_mfma_f32_16x16x32_bf16(af, B[5], aH[mt][1], 0, 0, 0); \
        } \
    }

        // 3-deep W pipeline: load s+2 in flight over 2 COMPWs (~480cy cover)
        LOADW(bfA, kgb + 0 * 32);
        LOADW(bfB, kgb + 1 * 32);
        LOADW(bfC, kgb + 2 * 32);
        COMPW(bfA, 0); LOADW(bfA, kgb + 3 * 32);
        COMPW(bfB, 1); LOADW(bfB, kgb + 4 * 32);
        COMPW(bfC, 2); LOADW(bfC, kgb + 5 * 32);
        COMPW(bfA, 3); LOADW(bfA, kgb + 6 * 32);
        COMPW(bfB, 4); LOADW(bfB, kgb + 7 * 32);
        COMPW(bfC, 5);
        COMPW(bfA, 6);
        COMPW(bfB, 7);
#undef LOADW
#undef COMPW
        __syncthreads();
    }

    // wave-local gate combine + Y write (plain stores; XCD-local visibility)
#pragma unroll
    for (int mt = 0; mt < 8; mt++) {
#pragma unroll
        for (int r = 0; r < 4; r++) {
            int row = mt * 16 + lq * 4 + r;
            int p = posL[row];
            if (p < 0) continue;
            int pi = pidxL[row];
#pragma unroll
            for (int ct = 0; ct < 2; ct++) {
                int cglob = cb + ct * 16 + lm;
                float rpre = a01[mt][ct][r]     + bi[cglob];
                float zpre = a01[mt][2 + ct][r] + bi[512 + cglob];
                float xn   = aX[mt][ct][r]      + bi[1024 + cglob];
                float hn   = aH[mt][ct][r]      + bhn[cglob];
                float rg = 1.f / (1.f + __expf(-rpre));
                float zg = 1.f / (1.f + __expf(-zpre));
                float targ = xn + rg * hn;
                float t2 = __expf(-2.f * fabsf(targ));
                float ng = copysignf((1.f - t2) / (1.f + t2), targ);
                float hp = 0.f;
                if (pi >= 0)
                    hp = YF32 ? ((const float*)Yv)[(size_t)pi * DDD + cglob]
                              : bf2f(((const u16*)Yv)[(size_t)pi * DDD + cglob]);
                else if (pi <= -2)
                    hp = hidden[(size_t)(-pi - 2) * DDD + cglob];
                float hnew = (1.f - zg) * ng + zg * hp;
                if (YF32) ((float*)Yv)[(size_t)p * DDD + cglob] = hnew;
                else      ((u16*)Yv)[(size_t)p * DDD + cglob] = f2bf(hnew);
            }
        }
    }
    __syncthreads();   // protect posL/As for next job; drains Y stores per wave
}

// ---------------- XCD-sharded GRU: per-XCD rounds (R7 sync verbatim) ----------------
template<bool YF32>
__global__ __launch_bounds__(256, 1) void gru_depth_k(
    const u16* __restrict__ E, const float* __restrict__ hidden,
    const u16* __restrict__ Wstk, const float* __restrict__ bi,
    const float* __restrict__ bhn,
    const int* __restrict__ list, const int* __restrict__ offs,
    const int* __restrict__ counts, const int* __restrict__ maxk,
    const int* __restrict__ pidxA,
    void* __restrict__ Yv, float* __restrict__ hid_out,
    int* __restrict__ xcdCnt)
{
    __shared__ u16 As[128 * 256];        // 64 KB
    __shared__ int posL[128], pidxL[128];
    __shared__ int sAnyH;
    const int tid = threadIdx.x;
    const int nblk = gridDim.x;
    const int e   = blockIdx.x & 7;      // XCD id (round-robin dispatch)
    const int xb  = blockIdx.x >> 3;     // block index within XCD
    const int nxb = nblk >> 3;           // blocks per XCD

    const int MKe = maxk[e];
    const int* cnt_e = counts + e * 512;
    const int* off_e = offs + e * 512;
    const int lb = e * 8192;             // this shard's list region
    int* cnt = xcdCnt + e * 32;          // this shard's barrier counter
    int round = 0;

    for (int k = 0; k <= MKe; k++) {
        const int nd = cnt_e[k];
        const int off = lb + off_e[k];
        const int njobs = ((nd + 127) >> 7) << 2;   // 128-row tiles * 4 panels
        for (int lj = xb; lj < njobs; lj += nxb) {
            gru_job<YF32>(E, hidden, Wstk, bi, bhn, list, pidxA, Yv,
                          off, nd, lj >> 2, lj & 3, As, posL, pidxL, &sAnyH);
        }
        // zero-fence per-XCD barrier (R7 verbatim): monotonic relaxed RMW +
        // relaxed spin; co-XCD L2 provides visibility of Y stores.
        ++round;
        __syncthreads();
        if (tid == 0) {
            __hip_atomic_fetch_add(cnt, 1, __ATOMIC_RELAXED, __HIP_MEMORY_SCOPE_AGENT);
            const int target = round * nxb;
            while (AL_RLX(cnt) < target) __builtin_amdgcn_s_sleep(1);
        }
        __syncthreads();
    }

    // final hidden for this shard's columns: b in [32e, 32e+32)
    for (int i = xb * 256 + tid; i < 32 * DDD; i += nxb * 256) {
        int b = 32 * e + (i >> 9), c = i & 511;
        size_t yi = (size_t)(65280 + b) * DDD + c;
        hid_out[(size_t)b * DDD + c] =
            YF32 ? ((const float*)Yv)[yi] : bf2f(((const u16*)Yv)[yi]);
    }
}

extern "C" void kernel_launch(void* const* d_in, const int* in_sizes, int n_in,
                              void* d_out, int out_size, void* d_ws, size_t ws_size,
                              hipStream_t stream)
{
    const float* hidden = (const float*)d_in[0];
    const float* obs    = (const float*)d_in[1];
    const int*   dones  = (const int*)d_in[2];
    const int*   avail  = (const int*)d_in[3];
    const float* Wm     = (const float*)d_in[4];
    const float* bm     = (const float*)d_in[5];
    const float* lns    = (const float*)d_in[6];
    const float* lnb    = (const float*)d_in[7];
    const float* Wi     = (const float*)d_in[8];
    const float* bi     = (const float*)d_in[9];
    const float* Wh     = (const float*)d_in[10];
    const float* bhn    = (const float*)d_in[11];
    const float* Wo     = (const float*)d_in[12];
    const float* bo     = (const float*)d_in[13];
    const float* ln2s   = (const float*)d_in[14];
    const float* ln2b   = (const float*)d_in[15];
    const float* Wa     = (const float*)d_in[16];
    const float* ba     = (const float*)d_in[17];
    float* out = (float*)d_out;

    // workspace layout
    char* w = (char*)d_ws;
    u16* Wstk = (u16*)w;  w += (size_t)1536 * 1024 * 2;      // 3 MB
    u16* WmT  = (u16*)w;  w += (size_t)3 * DDD * DDD * 2;
    u16* WoT  = (u16*)w;  w += (size_t)DDD * DDD * 2;
    int* meta = (int*)w;  w += 65536;
    int* counts = meta;              // 8*512
    int* offs   = meta + 4096;       // 8*512
    int* cursor = meta + 8192;       // 8*512
    int* maxk   = meta + 12288;      // 8
    int* xcdCnt = meta + 12544;      // 8 x stride-32
    int* keyA   = (int*)w;  w += (size_t)MMM * 4;
    int* pidxA  = (int*)w;  w += (size_t)MMM * 4;
    int* list   = (int*)w;  w += (size_t)MMM * 4;
    u16* P = (u16*)w;       w += (size_t)MMM * DDD * 2;      // 64 MB
    void* Yv = (void*)w;
    const size_t base = (size_t)(w - (char*)d_ws);
    const bool yf32 = (ws_size >= base + (size_t)MMM * DDD * 4);

    // prep: weight transposes + meta zero
    dim3 tgrid(16, 16);
    for (int l = 0; l < 3; l++)
        transpose_cvt_k<<<tgrid, 256, 0, stream>>>(Wm + (size_t)l * DDD * DDD, WmT + (size_t)l * DDD * DDD, DDD);
    transpose_cvt_k<<<tgrid, 256, 0, stream>>>(Wo, WoT, DDD);
    for (int g = 0; g < 3; g++) {
        transpose_cvt_k<<<tgrid, 256, 0, stream>>>(Wi + (size_t)g * DDD * DDD, Wstk + (size_t)g * 512 * 1024, 1024);
        transpose_cvt_k<<<tgrid, 256, 0, stream>>>(Wh + (size_t)g * DDD * DDD, Wstk + (size_t)g * 512 * 1024 + 512, 1024);
    }
    hipMemsetAsync(meta, 0, 65536, stream);

    // per-XCD key lists (done-first within each shard)
    depth_build_k<<<1, 256, 0, stream>>>(dones, keyA, pidxA, counts, maxk);
    scan_k<<<1, 64, 0, stream>>>(counts, offs);
    scatter_k<<<MMM / 256, 256, 0, stream>>>(keyA, offs, cursor, list);

    // encoder: obs -> P -> Y -> P
    u16* Yq = (u16*)Yv;
    gemm_bf16_k<true><<<dim3(MMM / 128, 4), 256, 0, stream>>>(obs, WmT, bm, P, DDD);
    ln_relu_k<<<dim3(MMM / 4), 256, 0, stream>>>(P, lns, lnb);
    gemm_bf16_k<false><<<dim3(MMM / 128, 4), 256, 0, stream>>>(P, WmT + (size_t)DDD * DDD, bm + DDD, Yq, DDD);
    ln_relu_k<<<dim3(MMM / 4), 256, 0, stream>>>(Yq, lns + DDD, lnb + DDD);
    gemm_bf16_k<false><<<dim3(MMM / 128, 4), 256, 0, stream>>>(Yq, WmT + (size_t)2 * DDD * DDD, bm + 2 * DDD, P, DDD);
    ln_relu_k<<<dim3(MMM / 4), 256, 0, stream>>>(P, lns + 2 * DDD, lnb + 2 * DDD);

    // persistent-block XCD-sharded GRU; grid sized to guaranteed co-residency
    {
        const void* fptr = yf32 ? (const void*)gru_depth_k<true>
                                : (const void*)gru_depth_k<false>;
        int occ = 0;
        hipError_t err = hipOccupancyMaxActiveBlocksPerMultiprocessor(&occ, fptr, 256, 0);
        if (err != hipSuccess || occ < 1) occ = 1;
        if (occ > 4) occ = 4;
        dim3 grid(occ * 256);
        if (yf32)
            gru_depth_k<true><<<grid, 256, 0, stream>>>(
                P, hidden, Wstk, bi, bhn, list, offs, counts, maxk, pidxA,
                Yv, out, xcdCnt);
        else
            gru_depth_k<false><<<grid, 256, 0, stream>>>(
                P, hidden, Wstk, bi, bhn, list, offs, counts, maxk, pidxA,
                Yv, out, xcdCnt);
    }

    // head: Y -> P, LN, logits
    if (yf32)
        gemm_bf16_k<true><<<dim3(MMM / 128, 4), 256, 0, stream>>>(Yv, WoT, bo, P, DDD);
    else
        gemm_bf16_k<false><<<dim3(MMM / 128, 4), 256, 0, stream>>>(Yv, WoT, bo, P, DDD);
    ln_relu_k<<<dim3(MMM / 4), 256, 0, stream>>>(P, ln2s, ln2b);
    logits_k<<<dim3(MMM / 8), 256, 0, stream>>>(P, Wa, ba, avail, out + BBB * DDD);
}

// Round 10
// 1803.531 us; speedup vs baseline: 1.1595x; 1.1595x over previous
//
#include <hip/hip_runtime.h>
#include <hip/hip_bf16.h>
#include <math.h>

// PPOActorRNN on MI355X — round 14: R7 base + split-phase (deep-MLP) staging.
// R9 regressed (128-row tiles, 1 blk/CU): concurrency > W-reuse. Little's law
// on R7's 366 GB/s => only ~1 outstanding 16B load per thread: the staging
// loop's global_load->ds_write interleave forces vmcnt(0) per element, i.e.
// the 8 staging loads SERIALIZE (~15-25us/job latency) — that is the real
// per-round cost (not sync, not W bytes; falsified in R5-R9).
// Fix: per-row source-pointer tables (E/Y/Hq/zero, all bf16 via pre-converted
// hidden) + staging as [8 branchless loads -> regs] then [8 LDS writes]:
// 8-deep MLP, ~8x lower staging latency. Everything else R7 verbatim
// (64-row tiles, XCD-sharded, zero-fence relaxed-RMW barrier: 879us GRU).

#define TTT 256
#define BBB 256
#define DDD 512
#define ACT 32
#define MMM (TTT*BBB)

typedef short bf16x8 __attribute__((ext_vector_type(8)));
typedef float f32x4 __attribute__((ext_vector_type(4)));
typedef unsigned short u16;

__device__ inline u16 f2bf(float f) {
    unsigned int u = __float_as_uint(f);
    u += 0x7fffu + ((u >> 16) & 1u);
    return (u16)(u >> 16);
}
__device__ inline float bf2f(u16 h) { return __uint_as_float(((unsigned int)h) << 16); }

#define AL_RLX(p)  __hip_atomic_load((p), __ATOMIC_RELAXED, __HIP_MEMORY_SCOPE_AGENT)

// ---------------- transpose + cvt: out[n*ostride + k] = bf16(in[k*512 + n]) ----
__global__ __launch_bounds__(256) void transpose_cvt_k(
    const float* __restrict__ in, u16* __restrict__ out, int ostride)
{
    __shared__ float tile[32][33];
    const int c = threadIdx.x & 31;
    const int r0 = threadIdx.x >> 5;
    const int bx = blockIdx.x, by = blockIdx.y;
#pragma unroll
    for (int p = 0; p < 4; p++) {
        int r = r0 + p * 8;
        tile[r][c] = in[(size_t)(by * 32 + r) * DDD + bx * 32 + c];
    }
    __syncthreads();
#pragma unroll
    for (int p = 0; p < 4; p++) {
        int r = r0 + p * 8;
        out[(size_t)(bx * 32 + r) * ostride + by * 32 + c] = f2bf(tile[c][r]);
    }
}

// ---------------- hidden f32 -> bf16 row copy (Hq) ----------------
__global__ __launch_bounds__(256) void cvt_hidden_k(
    const float* __restrict__ in, u16* __restrict__ out)
{
    int i = blockIdx.x * 256 + threadIdx.x;      // 16384 threads x 8 elems
    const float* s = in + (size_t)i * 8;
    float4 a0 = *(const float4*)s;
    float4 a1 = *(const float4*)(s + 4);
    bf16x8 v;
    v[0] = (short)f2bf(a0.x); v[1] = (short)f2bf(a0.y);
    v[2] = (short)f2bf(a0.z); v[3] = (short)f2bf(a0.w);
    v[4] = (short)f2bf(a1.x); v[5] = (short)f2bf(a1.y);
    v[6] = (short)f2bf(a1.z); v[7] = (short)f2bf(a1.w);
    *(bf16x8*)(out + (size_t)i * 8) = v;
}

// ---------------- MFMA GEMM (parallel phases), unchanged ----------------
template<bool AF32>
__global__ __launch_bounds__(256) void gemm_bf16_k(
    const void* __restrict__ Aptr, const u16* __restrict__ Bt,
    const float* __restrict__ bias, u16* __restrict__ C, int N)
{
    __shared__ u16 As[128 * 64];
    __shared__ u16 Bs[128 * 64];
    const int tid = threadIdx.x;
    const int row0 = blockIdx.x * 128;
    const int col0 = blockIdx.y * 128;
    const int lane = tid & 63, wid = tid >> 6;
    const int wr = wid >> 1, wc = wid & 1;
    const int lm = lane & 15, lq = lane >> 4;

    f32x4 acc[4][4];
#pragma unroll
    for (int i = 0; i < 4; i++)
#pragma unroll
        for (int j = 0; j < 4; j++) acc[i][j] = (f32x4){0.f, 0.f, 0.f, 0.f};

    for (int kc = 0; kc < 8; kc++) {
        const int k0 = kc * 64;
#pragma unroll
        for (int p = 0; p < 4; p++) {
            int g = p * 256 + tid;
            int row = g >> 3, j = g & 7;
            bf16x8 v;
            if (AF32) {
                const float* s = (const float*)Aptr + (size_t)(row0 + row) * DDD + k0 + j * 8;
                float4 a0 = *(const float4*)s;
                float4 a1 = *(const float4*)(s + 4);
                v[0] = (short)f2bf(a0.x); v[1] = (short)f2bf(a0.y);
                v[2] = (short)f2bf(a0.z); v[3] = (short)f2bf(a0.w);
                v[4] = (short)f2bf(a1.x); v[5] = (short)f2bf(a1.y);
                v[6] = (short)f2bf(a1.z); v[7] = (short)f2bf(a1.w);
            } else {
                v = *(const bf16x8*)((const u16*)Aptr + (size_t)(row0 + row) * DDD + k0 + j * 8);
            }
            *(bf16x8*)(As + row * 64 + ((j ^ (row & 7)) << 3)) = v;
        }
#pragma unroll
        for (int p = 0; p < 4; p++) {
            int g = p * 256 + tid;
            int n = g >> 3, j = g & 7;
            bf16x8 v = *(const bf16x8*)(Bt + (size_t)(col0 + n) * DDD + k0 + j * 8);
            *(bf16x8*)(Bs + n * 64 + ((j ^ (n & 7)) << 3)) = v;
        }
        __syncthreads();
#pragma unroll
        for (int ks = 0; ks < 2; ks++) {
            bf16x8 af[4], bfr[4];
#pragma unroll
            for (int i = 0; i < 4; i++) {
                int row = wr * 64 + i * 16 + lm;
                af[i] = *(const bf16x8*)(As + row * 64 + (((ks * 4 + lq) ^ (row & 7)) << 3));
            }
#pragma unroll
            for (int j = 0; j < 4; j++) {
                int n = wc * 64 + j * 16 + lm;
                bfr[j] = *(const bf16x8*)(Bs + n * 64 + (((ks * 4 + lq) ^ (n & 7)) << 3));
            }
#pragma unroll
            for (int i = 0; i < 4; i++)
#pragma unroll
                for (int j = 0; j < 4; j++)
                    acc[i][j] = __builtin_amdgcn_mfma_f32_16x16x32_bf16(af[i], bfr[j], acc[i][j], 0, 0, 0);
        }
        __syncthreads();
    }
#pragma unroll
    for (int j = 0; j < 4; j++) {
        int col = col0 + wc * 64 + j * 16 + lm;
        float bj = bias[col];
#pragma unroll
        for (int i = 0; i < 4; i++) {
            int rb = row0 + wr * 64 + i * 16 + lq * 4;
#pragma unroll
            for (int r = 0; r < 4; r++)
                C[(size_t)(rb + r) * N + col] = f2bf(acc[i][j][r] + bj);
        }
    }
}

// ---------------- LayerNorm + ReLU in-place on bf16 [M x 512] ----------------
__global__ __launch_bounds__(256) void ln_relu_k(
    u16* __restrict__ X, const float* __restrict__ gamma, const float* __restrict__ beta)
{
    const int tid = threadIdx.x;
    const int lane = tid & 63;
    const size_t row = (size_t)blockIdx.x * 4 + (tid >> 6);
    const int c0 = lane * 8;
    u16* px = X + row * DDD + c0;
    bf16x8 v = *(const bf16x8*)px;
    float f[8]; float s = 0.f, s2 = 0.f;
#pragma unroll
    for (int i = 0; i < 8; i++) { f[i] = bf2f((u16)v[i]); s += f[i]; s2 += f[i] * f[i]; }
#pragma unroll
    for (int off = 32; off; off >>= 1) { s += __shfl_xor(s, off); s2 += __shfl_xor(s2, off); }
    float mu = s * (1.f / (float)DDD);
    float rs = rsqrtf(s2 * (1.f / (float)DDD) - mu * mu + 1e-6f);
    float4 g0 = *(const float4*)(gamma + c0), g1 = *(const float4*)(gamma + c0 + 4);
    float4 b0 = *(const float4*)(beta + c0),  b1 = *(const float4*)(beta + c0 + 4);
    float gg[8] = {g0.x, g0.y, g0.z, g0.w, g1.x, g1.y, g1.z, g1.w};
    float bb[8] = {b0.x, b0.y, b0.z, b0.w, b1.x, b1.y, b1.z, b1.w};
    bf16x8 o;
#pragma unroll
    for (int i = 0; i < 8; i++) {
        float yv = (f[i] - mu) * rs * gg[i] + bb[i];
        o[i] = (short)f2bf(fmaxf(yv, 0.f));
    }
    *(bf16x8*)px = o;
}

// ---------------- logits ----------------
__global__ __launch_bounds__(256) void logits_k(
    const u16* __restrict__ AM, const float* __restrict__ Wa,
    const float* __restrict__ ba, const int* __restrict__ avail,
    float* __restrict__ out)
{
    __shared__ float xs[8][DDD];
    const int tid = threadIdx.x;
    const size_t row0 = (size_t)blockIdx.x * 8;
    for (int g = tid; g < 8 * 64; g += 256) {
        int r = g >> 6, c8 = (g & 63) * 8;
        bf16x8 v = *(const bf16x8*)(AM + (row0 + r) * DDD + c8);
#pragma unroll
        for (int i = 0; i < 8; i++) xs[r][c8 + i] = bf2f((u16)v[i]);
    }
    __syncthreads();
    const int r = tid >> 5, a = tid & 31;
    float acc = 0.f;
    for (int k = 0; k < DDD; k += 4) {
        float4 xv = *(const float4*)&xs[r][k];
        acc = fmaf(xv.x, Wa[(k + 0) * ACT + a], acc);
        acc = fmaf(xv.y, Wa[(k + 1) * ACT + a], acc);
        acc = fmaf(xv.z, Wa[(k + 2) * ACT + a], acc);
        acc = fmaf(xv.w, Wa[(k + 3) * ACT + a], acc);
    }
    size_t o = (row0 + r) * ACT + a;
    float v = acc + ba[a];
    if (avail[o] == 0) v -= 1e10f;
    out[o] = v;
}

// ---------------- list building (per-XCD buckets) — R7 verbatim ----------------
__global__ __launch_bounds__(256) void depth_build_k(
    const int* __restrict__ dones,
    int* __restrict__ keyA, int* __restrict__ pidxA,
    int* __restrict__ counts, int* __restrict__ maxk)
{
    __shared__ int lc[8 * 512];
    __shared__ int lmax[8];
    const int b = threadIdx.x;
    const int e = b >> 5;
    for (int i = b; i < 8 * 512; i += 256) lc[i] = 0;
    if (b < 8) lmax[b] = 0;
    __syncthreads();
    int dprev = 0, mx = 0;
    for (int t = 0; t < TTT; t++) {
        int pos = t * BBB + b;
        int d, pi, k;
        if (dones[pos] != 0)       { d = 0; pi = -1;       k = 0; }
        else if (t == 0)           { d = 0; pi = -2 - b;   k = 1; }
        else                       { d = dprev + 1; pi = pos - BBB; k = d + 1; }
        keyA[pos] = k; pidxA[pos] = pi;
        atomicAdd(&lc[e * 512 + k], 1);
        mx = max(mx, k);
        dprev = d;
    }
    atomicMax(&lmax[e], mx);
    __syncthreads();
    for (int i = b; i < 8 * 512; i += 256) counts[i] = lc[i];
    if (b < 8) maxk[b] = lmax[b];
}

__global__ void scan_k(const int* __restrict__ counts, int* __restrict__ offs)
{
    int e = threadIdx.x;
    if (e < 8) {
        int s = 0;
        for (int i = 0; i < 512; i++) { offs[e * 512 + i] = s; s += counts[e * 512 + i]; }
    }
}

__global__ __launch_bounds__(256) void scatter_k(
    const int* __restrict__ keyA, const int* __restrict__ offs,
    int* __restrict__ cursor, int* __restrict__ list)
{
    __shared__ int lcnt[8 * 512];
    __shared__ int lbase[8 * 512];
    const int tid = threadIdx.x;
    for (int i = tid; i < 8 * 512; i += 256) lcnt[i] = 0;
    __syncthreads();
    int pos = blockIdx.x * 256 + tid;
    int b = pos & 255;
    int e = b >> 5;
    int k = keyA[pos];
    int rank = atomicAdd(&lcnt[e * 512 + k], 1);
    __syncthreads();
    for (int q = tid; q < 8 * 512; q += 256) {
        int c = lcnt[q];
        lbase[q] = c ? atomicAdd(&cursor[q], c) : 0;
    }
    __syncthreads();
    list[e * 8192 + offs[e * 512 + k] + lbase[e * 512 + k] + rank] = pos;
}

// ---------------- GRU job body: split-phase staging ----------------
template<bool YF32>
__device__ __forceinline__ void gru_job(
    const u16* __restrict__ E, const float* __restrict__ hidden,
    const u16* __restrict__ Hq, const u16* __restrict__ zrow,
    const u16* __restrict__ Wstk, const float* __restrict__ bi,
    const float* __restrict__ bhn,
    const int* __restrict__ list, const int* __restrict__ pidxA,
    void* __restrict__ Yv,
    int off, int nd, int rt, int panel,
    u16* As, int* posL, int* pidxL, int* sAnyH,
    const u16** srcE, const u16** srcH)
{
    const int tid = threadIdx.x;
    const int w = tid >> 6, lane = tid & 63;
    const int lm = lane & 15, lq = lane >> 4;

    bool hasH = false;
    if (tid < 64) {
        int idx = rt * 64 + tid;
        int p = (idx < nd) ? list[off + idx] : -1;
        int pi = (p >= 0) ? pidxA[p] : -1;
        posL[tid] = p;
        pidxL[tid] = pi;
        hasH = (p >= 0) && (pi != -1);
        // source tables (all bf16-typed; YF32's Y handled via cast on load)
        srcE[tid] = (p >= 0) ? (E + (size_t)p * DDD) : zrow;
        const u16* h;
        if (p < 0 || pi == -1)  h = zrow;
        else if (pi >= 0)       h = YF32 ? (const u16*)((const float*)Yv + (size_t)pi * DDD)
                                         : ((const u16*)Yv + (size_t)pi * DDD);
        else                    h = YF32 ? (const u16*)(hidden + (size_t)(-pi - 2) * DDD)
                                         : (Hq + (size_t)(-pi - 2) * DDD);
        srcH[tid] = h;
        unsigned long long m = __ballot(hasH);
        if (tid == 0) *sAnyH = (m != 0ULL);
    }
    __syncthreads();
    const bool skipH = !(*sAnyH);

    f32x4 a01[4][4], aX[4][2], aH[4][2];
#pragma unroll
    for (int mt = 0; mt < 4; mt++) {
#pragma unroll
        for (int q = 0; q < 4; q++) a01[mt][q] = (f32x4){0.f, 0.f, 0.f, 0.f};
#pragma unroll
        for (int q = 0; q < 2; q++) {
            aX[mt][q] = (f32x4){0.f, 0.f, 0.f, 0.f};
            aH[mt][q] = (f32x4){0.f, 0.f, 0.f, 0.f};
        }
    }

    const int cb = panel * 128 + w * 32;
    const u16* wp[6];
#pragma unroll
    for (int ct = 0; ct < 6; ct++) {
        int gate = ct >> 1;
        int nglob = gate * 512 + cb + ((ct & 1) << 4) + lm;
        wp[ct] = Wstk + (size_t)nglob * 1024 + lq * 8;
    }

    const int nkc = skipH ? 2 : 4;
    for (int kc = 0; kc < nkc; kc++) {
        // ---- split-phase staging: all loads first (8-deep MLP), then LDS ----
        const bool eHalf = (kc < 2);
        const int koff = (kc & 1) * 256;          // u16-element offset in row
        if (eHalf || !YF32) {
            bf16x8 sv[8];
#pragma unroll
            for (int it = 0; it < 8; it++) {
                int g = it * 256 + tid;
                int row = g >> 5, jg = g & 31;
                const u16* s = (eHalf ? srcE[row] : srcH[row]) + koff + jg * 8;
                sv[it] = *(const bf16x8*)s;
            }
#pragma unroll
            for (int it = 0; it < 8; it++) {
                int g = it * 256 + tid;
                int row = g >> 5, jg = g & 31;
                *(bf16x8*)(As + row * 256 + ((jg ^ (row & 31)) << 3)) = sv[it];
            }
        } else {
            // YF32 H-half: sources are f32 rows; 2 batches of 4 (reg budget)
#pragma unroll
            for (int b2 = 0; b2 < 2; b2++) {
                float4 fv[4][2];
#pragma unroll
                for (int q = 0; q < 4; q++) {
                    int it = b2 * 4 + q;
                    int g = it * 256 + tid;
                    int row = g >> 5, jg = g & 31;
                    const float* s = (const float*)srcH[row] + koff + jg * 8;
                    fv[q][0] = *(const float4*)s;
                    fv[q][1] = *(const float4*)(s + 4);
                }
#pragma unroll
                for (int q = 0; q < 4; q++) {
                    int it = b2 * 4 + q;
                    int g = it * 256 + tid;
                    int row = g >> 5, jg = g & 31;
                    bf16x8 v;
                    v[0] = (short)f2bf(fv[q][0].x); v[1] = (short)f2bf(fv[q][0].y);
                    v[2] = (short)f2bf(fv[q][0].z); v[3] = (short)f2bf(fv[q][0].w);
                    v[4] = (short)f2bf(fv[q][1].x); v[5] = (short)f2bf(fv[q][1].y);
                    v[6] = (short)f2bf(fv[q][1].z); v[7] = (short)f2bf(fv[q][1].w);
                    *(bf16x8*)(As + row * 256 + ((jg ^ (row & 31)) << 3)) = v;
                }
            }
        }
        __syncthreads();

        const bool xpart = (kc < 2);
        const int kgb = kc * 256;
        bf16x8 bfA[6], bfB[6];

#define LOADW(B, KG) \
    _Pragma("unroll") \
    for (int ct = 0; ct < 6; ct++) B[ct] = *(const bf16x8*)(wp[ct] + (KG));

#define COMPW(B, S) \
    _Pragma("unroll") \
    for (int mt = 0; mt < 4; mt++) { \
        int row = mt * 16 + lm; \
        int jgr = (S) * 4 + lq; \
        bf16x8 af = *(const bf16x8*)(As + row * 256 + ((jgr ^ (row & 31)) << 3)); \
        a01[mt][0] = __builtin_amdgcn_mfma_f32_16x16x32_bf16(af, B[0], a01[mt][0], 0, 0, 0); \
        a01[mt][1] = __builtin_amdgcn_mfma_f32_16x16x32_bf16(af, B[1], a01[mt][1], 0, 0, 0); \
        a01[mt][2] = __builtin_amdgcn_mfma_f32_16x16x32_bf16(af, B[2], a01[mt][2], 0, 0, 0); \
        a01[mt][3] = __builtin_amdgcn_mfma_f32_16x16x32_bf16(af, B[3], a01[mt][3], 0, 0, 0); \
        if (xpart) { \
            aX[mt][0] = __builtin_amdgcn_mfma_f32_16x16x32_bf16(af, B[4], aX[mt][0], 0, 0, 0); \
            aX[mt][1] = __builtin_amdgcn_mfma_f32_16x16x32_bf16(af, B[5], aX[mt][1], 0, 0, 0); \
        } else { \
            aH[mt][0] = __builtin_amdgcn_mfma_f32_16x16x32_bf16(af, B[4], aH[mt][0], 0, 0, 0); \
            aH[mt][1] = __builtin_amdgcn_mfma_f32_16x16x32_bf16(af, B[5], aH[mt][1], 0, 0, 0); \
        } \
    }

        LOADW(bfA, kgb + 0 * 32);
#pragma unroll
        for (int sp = 0; sp < 4; sp++) {
            const int s0 = sp * 2, s1 = sp * 2 + 1;
            LOADW(bfB, kgb + s1 * 32);
            COMPW(bfA, s0);
            if (sp < 3) { LOADW(bfA, kgb + (s1 + 1) * 32); }
            COMPW(bfB, s1);
        }
#undef LOADW
#undef COMPW
        __syncthreads();
    }

    // wave-local gate combine + Y write (plain stores; XCD-local visibility)
#pragma unroll
    for (int mt = 0; mt < 4; mt++) {
#pragma unroll
        for (int r = 0; r < 4; r++) {
            int row = mt * 16 + lq * 4 + r;
            int p = posL[row];
            if (p < 0) continue;
            int pi = pidxL[row];
#pragma unroll
            for (int ct = 0; ct < 2; ct++) {
                int cglob = cb + ct * 16 + lm;
                float rpre = a01[mt][ct][r]     + bi[cglob];
                float zpre = a01[mt][2 + ct][r] + bi[512 + cglob];
                float xn   = aX[mt][ct][r]      + bi[1024 + cglob];
                float hn   = aH[mt][ct][r]      + bhn[cglob];
                float rg = 1.f / (1.f + __expf(-rpre));
                float zg = 1.f / (1.f + __expf(-zpre));
                float targ = xn + rg * hn;
                float t2 = __expf(-2.f * fabsf(targ));
                float ng = copysignf((1.f - t2) / (1.f + t2), targ);
                float hp = 0.f;
                if (pi >= 0)
                    hp = YF32 ? ((const float*)Yv)[(size_t)pi * DDD + cglob]
                              : bf2f(((const u16*)Yv)[(size_t)pi * DDD + cglob]);
                else if (pi <= -2)
                    hp = hidden[(size_t)(-pi - 2) * DDD + cglob];
                float hnew = (1.f - zg) * ng + zg * hp;
                if (YF32) ((float*)Yv)[(size_t)p * DDD + cglob] = hnew;
                else      ((u16*)Yv)[(size_t)p * DDD + cglob] = f2bf(hnew);
            }
        }
    }
    __syncthreads();   // protect posL/As/tables for next job
}

// ---------------- XCD-sharded GRU (R7 sync verbatim) ----------------
template<bool YF32>
__global__ __launch_bounds__(256, 2) void gru_depth_k(
    const u16* __restrict__ E, const float* __restrict__ hidden,
    const u16* __restrict__ Hq, const u16* __restrict__ zrow,
    const u16* __restrict__ Wstk, const float* __restrict__ bi,
    const float* __restrict__ bhn,
    const int* __restrict__ list, const int* __restrict__ offs,
    const int* __restrict__ counts, const int* __restrict__ maxk,
    const int* __restrict__ pidxA,
    void* __restrict__ Yv, float* __restrict__ hid_out,
    int* __restrict__ xcdCnt)
{
    __shared__ u16 As[64 * 256];         // 32 KB
    __shared__ int posL[64], pidxL[64];
    __shared__ const u16* srcE[64];
    __shared__ const u16* srcH[64];
    __shared__ int sAnyH;
    const int tid = threadIdx.x;
    const int nblk = gridDim.x;
    const int e   = blockIdx.x & 7;      // XCD id (round-robin dispatch)
    const int xb  = blockIdx.x >> 3;     // block index within XCD
    const int nxb = nblk >> 3;           // blocks per XCD

    const int MKe = maxk[e];
    const int* cnt_e = counts + e * 512;
    const int* off_e = offs + e * 512;
    const int lb = e * 8192;             // this shard's list region
    int* cnt = xcdCnt + e * 32;          // this shard's barrier counter
    int round = 0;

    for (int k = 0; k <= MKe; k++) {
        const int nd = cnt_e[k];
        const int off = lb + off_e[k];
        const int njobs = ((nd + 63) >> 6) << 2;
        for (int lj = xb; lj < njobs; lj += nxb) {
            gru_job<YF32>(E, hidden, Hq, zrow, Wstk, bi, bhn, list, pidxA, Yv,
                          off, nd, lj >> 2, lj & 3, As, posL, pidxL, &sAnyH,
                          srcE, srcH);
        }
        // zero-fence per-XCD barrier (R7 verbatim)
        ++round;
        __syncthreads();
        if (tid == 0) {
            __hip_atomic_fetch_add(cnt, 1, __ATOMIC_RELAXED, __HIP_MEMORY_SCOPE_AGENT);
            const int target = round * nxb;
            while (AL_RLX(cnt) < target) __builtin_amdgcn_s_sleep(1);
        }
        __syncthreads();
    }

    // final hidden for this shard's columns: b in [32e, 32e+32)
    for (int i = xb * 256 + tid; i < 32 * DDD; i += nxb * 256) {
        int b = 32 * e + (i >> 9), c = i & 511;
        size_t yi = (size_t)(65280 + b) * DDD + c;
        hid_out[(size_t)b * DDD + c] =
            YF32 ? ((const float*)Yv)[yi] : bf2f(((const u16*)Yv)[yi]);
    }
}

extern "C" void kernel_launch(void* const* d_in, const int* in_sizes, int n_in,
                              void* d_out, int out_size, void* d_ws, size_t ws_size,
                              hipStream_t stream)
{
    const float* hidden = (const float*)d_in[0];
    const float* obs    = (const float*)d_in[1];
    const int*   dones  = (const int*)d_in[2];
    const int*   avail  = (const int*)d_in[3];
    const float* Wm     = (const float*)d_in[4];
    const float* bm     = (const float*)d_in[5];
    const float* lns    = (const float*)d_in[6];
    const float* lnb    = (const float*)d_in[7];
    const float* Wi     = (const float*)d_in[8];
    const float* bi     = (const float*)d_in[9];
    const float* Wh     = (const float*)d_in[10];
    const float* bhn    = (const float*)d_in[11];
    const float* Wo     = (const float*)d_in[12];
    const float* bo     = (const float*)d_in[13];
    const float* ln2s   = (const float*)d_in[14];
    const float* ln2b   = (const float*)d_in[15];
    const float* Wa     = (const float*)d_in[16];
    const float* ba     = (const float*)d_in[17];
    float* out = (float*)d_out;

    // workspace layout
    char* w = (char*)d_ws;
    u16* Wstk = (u16*)w;  w += (size_t)1536 * 1024 * 2;      // 3 MB
    u16* WmT  = (u16*)w;  w += (size_t)3 * DDD * DDD * 2;
    u16* WoT  = (u16*)w;  w += (size_t)DDD * DDD * 2;
    u16* Hq   = (u16*)w;  w += (size_t)BBB * DDD * 2;        // 256 KB bf16 hidden
    u16* zrow = (u16*)w;  w += 4096;                         // zero row (covers f32 too)
    int* meta = (int*)w;  w += 65536;
    int* counts = meta;              // 8*512
    int* offs   = meta + 4096;       // 8*512
    int* cursor = meta + 8192;       // 8*512
    int* maxk   = meta + 12288;      // 8
    int* xcdCnt = meta + 12544;      // 8 x stride-32
    int* keyA   = (int*)w;  w += (size_t)MMM * 4;
    int* pidxA  = (int*)w;  w += (size_t)MMM * 4;
    int* list   = (int*)w;  w += (size_t)MMM * 4;
    u16* P = (u16*)w;       w += (size_t)MMM * DDD * 2;      // 64 MB
    void* Yv = (void*)w;
    const size_t base = (size_t)(w - (char*)d_ws);
    const bool yf32 = (ws_size >= base + (size_t)MMM * DDD * 4);

    // prep: weight transposes + hidden cvt + zero/meta init
    dim3 tgrid(16, 16);
    for (int l = 0; l < 3; l++)
        transpose_cvt_k<<<tgrid, 256, 0, stream>>>(Wm + (size_t)l * DDD * DDD, WmT + (size_t)l * DDD * DDD, DDD);
    transpose_cvt_k<<<tgrid, 256, 0, stream>>>(Wo, WoT, DDD);
    for (int g = 0; g < 3; g++) {
        transpose_cvt_k<<<tgrid, 256, 0, stream>>>(Wi + (size_t)g * DDD * DDD, Wstk + (size_t)g * 512 * 1024, 1024);
        transpose_cvt_k<<<tgrid, 256, 0, stream>>>(Wh + (size_t)g * DDD * DDD, Wstk + (size_t)g * 512 * 1024 + 512, 1024);
    }
    cvt_hidden_k<<<BBB * DDD / 8 / 256, 256, 0, stream>>>(hidden, Hq);
    hipMemsetAsync(zrow, 0, 4096, stream);
    hipMemsetAsync(meta, 0, 65536, stream);

    // per-XCD key lists (done-first within each shard)
    depth_build_k<<<1, 256, 0, stream>>>(dones, keyA, pidxA, counts, maxk);
    scan_k<<<1, 64, 0, stream>>>(counts, offs);
    scatter_k<<<MMM / 256, 256, 0, stream>>>(keyA, offs, cursor, list);

    // encoder: obs -> P -> Y -> P
    u16* Yq = (u16*)Yv;
    gemm_bf16_k<true><<<dim3(MMM / 128, 4), 256, 0, stream>>>(obs, WmT, bm, P, DDD);
    ln_relu_k<<<dim3(MMM / 4), 256, 0, stream>>>(P, lns, lnb);
    gemm_bf16_k<false><<<dim3(MMM / 128, 4), 256, 0, stream>>>(P, WmT + (size_t)DDD * DDD, bm + DDD, Yq, DDD);
    ln_relu_k<<<dim3(MMM / 4), 256, 0, stream>>>(Yq, lns + DDD, lnb + DDD);
    gemm_bf16_k<false><<<dim3(MMM / 128, 4), 256, 0, stream>>>(Yq, WmT + (size_t)2 * DDD * DDD, bm + 2 * DDD, P, DDD);
    ln_relu_k<<<dim3(MMM / 4), 256, 0, stream>>>(P, lns + 2 * DDD, lnb + 2 * DDD);

    // persistent-block XCD-sharded GRU; grid sized to guaranteed co-residency
    {
        const void* fptr = yf32 ? (const void*)gru_depth_k<true>
                                : (const void*)gru_depth_k<false>;
        int occ = 0;
        hipError_t err = hipOccupancyMaxActiveBlocksPerMultiprocessor(&occ, fptr, 256, 0);
        if (err != hipSuccess || occ < 1) occ = 2;
        if (occ > 4) occ = 4;
        dim3 grid(occ * 256);
        if (yf32)
            gru_depth_k<true><<<grid, 256, 0, stream>>>(
                P, hidden, Hq, zrow, Wstk, bi, bhn, list, offs, counts, maxk, pidxA,
                Yv, out, xcdCnt);
        else
            gru_depth_k<false><<<grid, 256, 0, stream>>>(
                P, hidden, Hq, zrow, Wstk, bi, bhn, list, offs, counts, maxk, pidxA,
                Yv, out, xcdCnt);
    }

    // head: Y -> P, LN, logits
    if (yf32)
        gemm_bf16_k<true><<<dim3(MMM / 128, 4), 256, 0, stream>>>(Yv, WoT, bo, P, DDD);
    else
        gemm_bf16_k<false><<<dim3(MMM / 128, 4), 256, 0, stream>>>(Yv, WoT, bo, P, DDD);
    ln_relu_k<<<dim3(MMM / 4), 256, 0, stream>>>(P, ln2s, ln2b);
    logits_k<<<dim3(MMM / 8), 256, 0, stream>>>(P, Wa, ba, avail, out + BBB * DDD);
}